// Round 4
// baseline (238.066 us; speedup 1.0000x reference)
//
#include <hip/hip_runtime.h>
#include <hip/hip_bf16.h>
#include <math.h>

#define H_DIM 768
#define E_NUM 8
#define DFF   3072
#define T_NUM 2048
#define PAIRS 4096   // T_NUM * top_k(=2), constant by construction

typedef __attribute__((ext_vector_type(8))) short          s16x8;
typedef __attribute__((ext_vector_type(4))) float          f32x4;
typedef __attribute__((ext_vector_type(4))) unsigned int   u32x4;
typedef __attribute__((ext_vector_type(4))) unsigned short u16x4;
typedef __attribute__((ext_vector_type(8))) unsigned short u16x8;

__device__ __forceinline__ unsigned short f2bf(float f) {
  unsigned int u = __builtin_bit_cast(unsigned int, f);
  u += 0x7FFFu + ((u >> 16) & 1u);     // round-to-nearest-even
  return (unsigned short)(u >> 16);
}

// branchless tanh-form GELU: x * sigmoid(1.59577*(x + 0.044715 x^3))
// exp2 arg folded; max |err vs erf-GELU| ~3e-4 (<< bf16 noise, threshold 5.7e-2)
__device__ __forceinline__ float gelu_fast(float x) {
  float t = x * x;
  float a = __builtin_fmaf(t, -0.10294221f, -2.3022082f);
  float w;
  asm("v_exp_f32 %0, %1" : "=v"(w) : "v"(x * a));
  float r;
  float d = 1.0f + w;
  asm("v_rcp_f32 %0, %1" : "=v"(r) : "v"(d));
  return x * r;
}

// ---------------- routing: logits -> softmax -> top2 -> renorm weights ---------------
// WgT staged in LDS (transposed), x as f32x4, WgT rows as b128 reads.
// 128 blocks x 16 tokens; each wave owns 4 tokens sequentially.
__global__ __launch_bounds__(256) void k_route(
    const float* __restrict__ x, const float* __restrict__ Wg,
    const float* __restrict__ bg, int* __restrict__ eidx,
    float* __restrict__ ew, int* __restrict__ counts) {
  __shared__ float WgT[E_NUM][H_DIM + 4];
  int tid = threadIdx.x;
#pragma unroll
  for (int i = 0; i < 6; ++i) {             // 1536 f32x4 = 6144 floats
    int q = i * 256 + tid;
    f32x4 v = *(const f32x4*)&Wg[q * 4];
#pragma unroll
    for (int j = 0; j < 4; ++j) {
      int idx = q * 4 + j;                   // idx = h*8 + e
      WgT[idx & 7][idx >> 3] = v[j];
    }
  }
  __syncthreads();
  int wave = tid >> 6, lane = tid & 63;
#pragma unroll
  for (int j = 0; j < 4; ++j) {
    int t = blockIdx.x * 16 + wave * 4 + j;
    const float* xr = x + (size_t)t * H_DIM;
    f32x4 xv[3];
#pragma unroll
    for (int i = 0; i < 3; ++i) xv[i] = *(const f32x4*)&xr[i * 256 + lane * 4];
    float acc[E_NUM];
#pragma unroll
    for (int e = 0; e < E_NUM; ++e) {
      float s = 0.f;
#pragma unroll
      for (int i = 0; i < 3; ++i) {
        f32x4 wv = *(const f32x4*)&WgT[e][i * 256 + lane * 4];
        s += xv[i][0] * wv[0] + xv[i][1] * wv[1] + xv[i][2] * wv[2] + xv[i][3] * wv[3];
      }
      acc[e] = s;
    }
#pragma unroll
    for (int e = 0; e < E_NUM; ++e) {
#pragma unroll
      for (int off = 32; off > 0; off >>= 1) acc[e] += __shfl_xor(acc[e], off);
    }
    if (lane == 0) {
      float l[E_NUM];
#pragma unroll
      for (int e = 0; e < E_NUM; ++e) l[e] = acc[e] + bg[e];
      int i0 = 0;
#pragma unroll
      for (int e = 1; e < E_NUM; ++e) if (l[e] > l[i0]) i0 = e;
      int i1 = (i0 == 0) ? 1 : 0;
#pragma unroll
      for (int e = 0; e < E_NUM; ++e) if (e != i0 && l[e] > l[i1]) i1 = e;
      float d  = expf(l[i1] - l[i0]);
      eidx[2 * t]     = i0;
      eidx[2 * t + 1] = i1;
      ew[2 * t]       = 1.f / (1.f + d);
      ew[2 * t + 1]   = d / (1.f + d);
      atomicAdd(&counts[i0], 1);
      atomicAdd(&counts[i1], 1);
    }
  }
}

__global__ void k_init(int* __restrict__ ctrl) {
  if (threadIdx.x < 32) ctrl[threadIdx.x] = 0;
}

__global__ void k_scan(const int* __restrict__ counts, int* __restrict__ offsets,
                       int* __restrict__ cursor) {
  if (threadIdx.x == 0) {
    int s = 0;
    for (int e = 0; e < E_NUM; ++e) { offsets[e] = s; cursor[e] = s; s += counts[e]; }
    offsets[E_NUM] = s;
  }
}

__global__ void k_scatter(const int* __restrict__ eidx, int* __restrict__ cursor,
                          int* __restrict__ tok_of, int* __restrict__ slot_of) {
  int t = blockIdx.x * blockDim.x + threadIdx.x;
  if (t >= T_NUM) return;
#pragma unroll
  for (int k = 0; k < 2; ++k) {
    int e = eidx[2 * t + k];
    int s = atomicAdd(&cursor[e], 1);
    tok_of[s] = t;
    slot_of[2 * t + k] = s;
  }
}

// gather x rows (fp32) into slot-ordered bf16 Xg
__global__ void k_gather(const float* __restrict__ x, const int* __restrict__ tok_of,
                         unsigned short* __restrict__ Xg) {
  int s = blockIdx.x;
  int lane = threadIdx.x;
  int t = tok_of[s];
  const f32x4* xr = (const f32x4*)(x + (size_t)t * H_DIM);
  u16x4* orow = (u16x4*)(Xg + (size_t)s * H_DIM);
#pragma unroll
  for (int i = 0; i < H_DIM / 256; ++i) {
    f32x4 v = xr[i * 64 + lane];
    u16x4 o;
    o[0] = f2bf(v[0]); o[1] = f2bf(v[1]); o[2] = f2bf(v[2]); o[3] = f2bf(v[3]);
    orow[i * 64 + lane] = o;
  }
}

// in: [E][R][C] fp32 -> out: [E][C][R] bf16 (B^T layout), 64x64 tiles, wide stores.
__global__ __launch_bounds__(256) void k_transpose_cast(
    const float* __restrict__ in, unsigned short* __restrict__ out, int R, int C) {
  __shared__ unsigned short tile[64][72];
  int e  = blockIdx.z;
  int c0 = blockIdx.x * 64, r0 = blockIdx.y * 64;
  const float* ip = in + (size_t)e * R * C;
  unsigned short* op = out + (size_t)e * R * C;
  int tid = threadIdx.x;
  int tx = tid & 15, ty = tid >> 4;
#pragma unroll
  for (int i = 0; i < 4; ++i) {
    int r = ty + 16 * i;
    f32x4 v = *(const f32x4*)&ip[(size_t)(r0 + r) * C + c0 + tx * 4];
    u16x4 o;
    o[0] = f2bf(v[0]); o[1] = f2bf(v[1]); o[2] = f2bf(v[2]); o[3] = f2bf(v[3]);
    *(u16x4*)&tile[r][tx * 4] = o;
  }
  __syncthreads();
  int c  = tid & 63;
  int rc = (tid >> 6) * 16;
#pragma unroll
  for (int h = 0; h < 2; ++h) {
    u16x8 o;
#pragma unroll
    for (int j = 0; j < 8; ++j) o[j] = tile[rc + h * 8 + j][c];
    *(u16x8*)&op[(size_t)(c0 + c) * R + r0 + rc + h * 8] = o;
  }
}

// m97-exact 128x128-tile GEMM: 4 waves (2x2 of 64x64), BK=64, SINGLE-buffered
// 32 KB LDS -> 4-5 resident blocks/CU (inter-block overlap is the pipeline).
// A [slots][KTOT] bf16, B^T [E][NDIM][KTOT] bf16, per-expert row segments.
// T2 swizzle (r2-verified, conflicts=0): linear LDS dest + permuted global
// source col + XOR'd ds_read. Balanced decode: nt inner, e mid, mt outermost.
template <int KTOT, int NT, int NSPLIT, bool GELU_OUT>
__global__ __launch_bounds__(256) void k_gemm(
    const unsigned short* __restrict__ A, const unsigned short* __restrict__ B,
    const float* __restrict__ bias, void* __restrict__ C,
    const int* __restrict__ counts, const int* __restrict__ offsets) {
  constexpr int NDIM = NT * 128;
  constexpr int KLEN = KTOT / NSPLIT;
  int l = blockIdx.x;
  int nt = l % NT;  l /= NT;
  int e  = l & 7;   l >>= 3;
  int part = l % NSPLIT;
  int mt = l / NSPLIT;
  int Me = counts[e];
  if (mt * 128 >= Me) return;
  int seg = offsets[e];

  __shared__ __align__(16) unsigned short Al[128 * 64];
  __shared__ __align__(16) unsigned short Bl[128 * 64];

  int tid  = threadIdx.x;
  int lane = tid & 63;
  int wave = tid >> 6;
  int wm = wave >> 1, wn = wave & 1;   // 2x2 waves, 64x64 each

  int sr   = tid >> 3;                               // staging row 0..31 per pass
  int scl  = (tid & 7) * 8;                          // linear LDS col (elems)
  int scs  = (((tid & 7) ^ (sr & 7)) * 8);           // swizzled global source col
  int rxor = (lane & 7) << 3;                        // read-side XOR (elems)

  f32x4 acc[4][4];
#pragma unroll
  for (int m = 0; m < 4; ++m)
#pragma unroll
    for (int n = 0; n < 4; ++n) acc[m][n] = (f32x4){0.f, 0.f, 0.f, 0.f};

  const unsigned short* Abase = A + (size_t)seg * KTOT;
  const unsigned short* Bbase = B + (size_t)e * NDIM * KTOT + (size_t)(nt * 128) * KTOT;
  const int kbeg = part * KLEN;

  for (int k0 = kbeg; k0 < kbeg + KLEN; k0 += 64) {
#pragma unroll
    for (int j = 0; j < 4; ++j) {
      int row = j * 32 + sr;
      int r = mt * 128 + row;
      r = (r < Me) ? r : (Me - 1);     // clamp (dup last row; stores predicated)
      const unsigned short* gp = Abase + (size_t)r * KTOT + k0 + scs;
      __builtin_amdgcn_global_load_lds(
          (__attribute__((address_space(1))) void*)gp,
          (__attribute__((address_space(3))) void*)&Al[row * 64 + scl], 16, 0, 0);
    }
#pragma unroll
    for (int j = 0; j < 4; ++j) {
      int row = j * 32 + sr;
      const unsigned short* gp = Bbase + (size_t)row * KTOT + k0 + scs;
      __builtin_amdgcn_global_load_lds(
          (__attribute__((address_space(1))) void*)gp,
          (__attribute__((address_space(3))) void*)&Bl[row * 64 + scl], 16, 0, 0);
    }
    __syncthreads();

#pragma unroll
    for (int kk = 0; kk < 2; ++kk) {
      int ko = kk * 32 + (lane >> 4) * 8;
      s16x8 af[4], bfr[4];
#pragma unroll
      for (int m = 0; m < 4; ++m) {
        int row = wm * 64 + m * 16 + (lane & 15);
        u32x4 v = *(const u32x4*)&Al[(row * 64 + ko) ^ rxor];
        af[m] = __builtin_bit_cast(s16x8, v);
      }
#pragma unroll
      for (int n = 0; n < 4; ++n) {
        int row = wn * 64 + n * 16 + (lane & 15);
        u32x4 v = *(const u32x4*)&Bl[(row * 64 + ko) ^ rxor];
        bfr[n] = __builtin_bit_cast(s16x8, v);
      }
#pragma unroll
      for (int m = 0; m < 4; ++m)
#pragma unroll
        for (int n = 0; n < 4; ++n)
          acc[m][n] = __builtin_amdgcn_mfma_f32_16x16x32_bf16(af[m], bfr[n], acc[m][n], 0, 0, 0);
    }
    __syncthreads();
  }

  // epilogue: C/D layout col = lane&15, row = (lane>>4)*4 + reg
  int rbase = mt * 128 + wm * 64;
  int cbase = nt * 128 + wn * 64;
#pragma unroll
  for (int m = 0; m < 4; ++m) {
#pragma unroll
    for (int n = 0; n < 4; ++n) {
      int col = cbase + n * 16 + (lane & 15);
      float bv = GELU_OUT ? bias[e * NDIM + col] : 0.f;
#pragma unroll
      for (int r = 0; r < 4; ++r) {
        int row = rbase + m * 16 + (lane >> 4) * 4 + r;
        if (row < Me) {
          float v = acc[m][n][r] + bv;
          size_t idx = ((size_t)part * PAIRS + seg + row) * NDIM + col;
          if constexpr (GELU_OUT) {
            ((unsigned short*)C)[idx] = f2bf(gelu_fast(v));
          } else {
            ((float*)C)[idx] = v;   // raw partial; bias added in combine
          }
        }
      }
    }
  }
}

// out[t] = w0*(sum_p P[p][s0] + b2[e0]) + w1*(sum_p P[p][s1] + b2[e1])
template <int NSPLIT>
__global__ void k_combine(const float* __restrict__ P, const int* __restrict__ slot_of,
                          const int* __restrict__ eidx, const float* __restrict__ ew,
                          const float* __restrict__ b2, float* __restrict__ out) {
  int t = blockIdx.x;
  int i = threadIdx.x;  // 192 threads * float4 = 768
  int s0 = slot_of[2 * t], s1 = slot_of[2 * t + 1];
  int e0 = eidx[2 * t],    e1 = eidx[2 * t + 1];
  float w0 = ew[2 * t], w1 = ew[2 * t + 1];
  f32x4 a = *(const f32x4*)&b2[e0 * H_DIM + i * 4];
  f32x4 c = *(const f32x4*)&b2[e1 * H_DIM + i * 4];
#pragma unroll
  for (int p = 0; p < NSPLIT; ++p) {
    f32x4 va = *(const f32x4*)&P[((size_t)p * PAIRS + s0) * H_DIM + i * 4];
    f32x4 vb = *(const f32x4*)&P[((size_t)p * PAIRS + s1) * H_DIM + i * 4];
    a[0] += va[0]; a[1] += va[1]; a[2] += va[2]; a[3] += va[3];
    c[0] += vb[0]; c[1] += vb[1]; c[2] += vb[2]; c[3] += vb[3];
  }
  f32x4 o;
  o[0] = w0 * a[0] + w1 * c[0];
  o[1] = w0 * a[1] + w1 * c[1];
  o[2] = w0 * a[2] + w1 * c[2];
  o[3] = w0 * a[3] + w1 * c[3];
  ((f32x4*)(out + (size_t)t * H_DIM))[i] = o;
}

extern "C" void kernel_launch(void* const* d_in, const int* in_sizes, int n_in,
                              void* d_out, int out_size, void* d_ws, size_t ws_size,
                              hipStream_t stream) {
  (void)in_sizes; (void)n_in; (void)out_size;
  const float* x  = (const float*)d_in[0];
  const float* Wg = (const float*)d_in[1];
  const float* bg = (const float*)d_in[2];
  const float* W1 = (const float*)d_in[3];
  const float* b1 = (const float*)d_in[4];
  const float* W2 = (const float*)d_in[5];
  const float* b2 = (const float*)d_in[6];
  float* out = (float*)d_out;

  char* w = (char*)d_ws;
  size_t off = 0;
  auto take = [&](size_t n) { void* p = w + off; off = (off + n + 255) & ~(size_t)255; return p; };
  int*   ctrl    = (int*)  take(64 * sizeof(int));
  int*   eidx    = (int*)  take(PAIRS * sizeof(int));
  float* ew      = (float*)take(PAIRS * sizeof(float));
  int*   slot_of = (int*)  take(PAIRS * sizeof(int));
  int*   tok_of  = (int*)  take(PAIRS * sizeof(int));
  unsigned short* Xg   = (unsigned short*)take((size_t)PAIRS * H_DIM * 2);
  unsigned short* Wb   = (unsigned short*)take((size_t)E_NUM * H_DIM * DFF * 2);  // W1b then W2b
  unsigned short* Hmid = (unsigned short*)take((size_t)PAIRS * DFF * 2);
  size_t p_off = off;
  float* P = (float*)(w + p_off);
  bool split4 = (p_off + (size_t)4 * PAIRS * H_DIM * sizeof(float)) <= ws_size;
  if (p_off + (size_t)PAIRS * H_DIM * sizeof(float) > ws_size) return;

  int* counts  = ctrl;
  int* cursor  = ctrl + 8;
  int* offsets = ctrl + 16;

  k_init<<<1, 64, 0, stream>>>(ctrl);
  k_route<<<T_NUM / 16, 256, 0, stream>>>(x, Wg, bg, eidx, ew, counts);
  k_scan<<<1, 64, 0, stream>>>(counts, offsets, cursor);
  k_scatter<<<T_NUM / 256, 256, 0, stream>>>(eidx, cursor, tok_of, slot_of);
  k_gather<<<PAIRS, 64, 0, stream>>>(x, tok_of, Xg);

  // W1 [E][768][3072] -> Wb [E][3072][768] bf16
  k_transpose_cast<<<dim3(DFF / 64, H_DIM / 64, E_NUM), 256, 0, stream>>>(W1, Wb, H_DIM, DFF);
  // GEMM1: 24 nt * 8 e * 16 mt = 3072 blocks (active ~768 = 3/CU)
  k_gemm<H_DIM, DFF / 128, 1, true><<<(DFF / 128) * E_NUM * 16, 256, 0, stream>>>(
      Xg, Wb, b1, Hmid, counts, offsets);

  // W2 [E][3072][768] -> Wb [E][768][3072] bf16 (reuse; stream order serializes)
  k_transpose_cast<<<dim3(H_DIM / 64, DFF / 64, E_NUM), 256, 0, stream>>>(W2, Wb, DFF, H_DIM);

  if (split4) {
    // GEMM2: 6 nt * 8 e * 4 part * 16 mt = 3072 blocks (active ~768 = 3/CU)
    k_gemm<DFF, H_DIM / 128, 4, false><<<(H_DIM / 128) * E_NUM * 4 * 16, 256, 0, stream>>>(
        Hmid, Wb, b2, P, counts, offsets);
    k_combine<4><<<T_NUM, 192, 0, stream>>>(P, slot_of, eidx, ew, b2, out);
  } else {
    k_gemm<DFF, H_DIM / 128, 1, false><<<(H_DIM / 128) * E_NUM * 16, 256, 0, stream>>>(
        Hmid, Wb, b2, P, counts, offsets);
    k_combine<1><<<T_NUM, 192, 0, stream>>>(P, slot_of, eidx, ew, b2, out);
  }
}

// Round 5
// 173.618 us; speedup vs baseline: 1.3712x; 1.3712x over previous
//
#include <hip/hip_runtime.h>
#include <hip/hip_bf16.h>
#include <math.h>

#define H_DIM 768
#define E_NUM 8
#define DFF   3072
#define T_NUM 2048
#define PAIRS 4096   // T_NUM * top_k(=2), constant by construction

typedef __attribute__((ext_vector_type(8))) short          s16x8;
typedef __attribute__((ext_vector_type(4))) float          f32x4;
typedef __attribute__((ext_vector_type(4))) unsigned int   u32x4;
typedef __attribute__((ext_vector_type(4))) unsigned short u16x4;
typedef __attribute__((ext_vector_type(8))) unsigned short u16x8;

__device__ __forceinline__ unsigned short f2bf(float f) {
  unsigned int u = __builtin_bit_cast(unsigned int, f);
  u += 0x7FFFu + ((u >> 16) & 1u);     // round-to-nearest-even
  return (unsigned short)(u >> 16);
}

// branchless tanh-form GELU: x * sigmoid(1.59577*(x + 0.044715 x^3))
// exp2 arg folded; max |err vs erf-GELU| ~3e-4 (<< bf16 noise, threshold 5.7e-2)
__device__ __forceinline__ float gelu_fast(float x) {
  float t = x * x;
  float a = __builtin_fmaf(t, -0.10294221f, -2.3022082f);
  float w;
  asm("v_exp_f32 %0, %1" : "=v"(w) : "v"(x * a));
  float r;
  float d = 1.0f + w;
  asm("v_rcp_f32 %0, %1" : "=v"(r) : "v"(d));
  return x * r;
}

// ---------------- routing: logits -> softmax -> top2 -> renorm weights ---------------
// NO global atomics (they were the 54 us stall: 4096 device-scope atomics on one
// cache line serialize at the cross-XCD coherence point). One wave per token;
// Wg row [h][0..7] loaded as 2x f32x4, h = i*64+lane fully coalesced.
__global__ __launch_bounds__(256) void k_route(
    const float* __restrict__ x, const float* __restrict__ Wg,
    const float* __restrict__ bg, int* __restrict__ eidx, float* __restrict__ ew) {
  int wave = threadIdx.x >> 6, lane = threadIdx.x & 63;
  int t = blockIdx.x * 4 + wave;
  const float* xr = x + (size_t)t * H_DIM;
  float acc[E_NUM];
#pragma unroll
  for (int e = 0; e < E_NUM; ++e) acc[e] = 0.f;
#pragma unroll
  for (int i = 0; i < H_DIM / 64; ++i) {
    int h = i * 64 + lane;
    float xv = xr[h];
    f32x4 w0 = *(const f32x4*)&Wg[h * 8];
    f32x4 w1 = *(const f32x4*)&Wg[h * 8 + 4];
    acc[0] += xv * w0[0]; acc[1] += xv * w0[1];
    acc[2] += xv * w0[2]; acc[3] += xv * w0[3];
    acc[4] += xv * w1[0]; acc[5] += xv * w1[1];
    acc[6] += xv * w1[2]; acc[7] += xv * w1[3];
  }
#pragma unroll
  for (int e = 0; e < E_NUM; ++e) {
#pragma unroll
    for (int off = 32; off > 0; off >>= 1) acc[e] += __shfl_xor(acc[e], off);
  }
  if (lane == 0) {
    float l[E_NUM];
#pragma unroll
    for (int e = 0; e < E_NUM; ++e) l[e] = acc[e] + bg[e];
    int i0 = 0;
#pragma unroll
    for (int e = 1; e < E_NUM; ++e) if (l[e] > l[i0]) i0 = e;
    int i1 = (i0 == 0) ? 1 : 0;
#pragma unroll
    for (int e = 0; e < E_NUM; ++e) if (e != i0 && l[e] > l[i1]) i1 = e;
    float d  = expf(l[i1] - l[i0]);
    eidx[2 * t]     = i0;
    eidx[2 * t + 1] = i1;
    ew[2 * t]       = 1.f / (1.f + d);
    ew[2 * t + 1]   = d / (1.f + d);
  }
}

// Single block: LDS histogram -> prefix -> LDS-atomic scatter. Replaces
// k_init/k_scan/k_scatter and all global atomics. Slot order within an expert
// is arbitrary; final output is bit-identical (row math is position-independent).
__global__ __launch_bounds__(256) void k_build(
    const int* __restrict__ eidx, int* __restrict__ counts, int* __restrict__ offsets,
    int* __restrict__ tok_of, int* __restrict__ slot_of) {
  __shared__ int cnt[E_NUM];
  __shared__ int cur[E_NUM];
  int tid = threadIdx.x;
  if (tid < E_NUM) cnt[tid] = 0;
  __syncthreads();
#pragma unroll
  for (int i = 0; i < PAIRS / 256; ++i)
    atomicAdd(&cnt[eidx[i * 256 + tid]], 1);
  __syncthreads();
  if (tid == 0) {
    int s = 0;
    for (int e = 0; e < E_NUM; ++e) { cur[e] = s; s += cnt[e]; }
  }
  __syncthreads();
  if (tid < E_NUM) { counts[tid] = cnt[tid]; offsets[tid] = cur[tid]; }
#pragma unroll
  for (int i = 0; i < PAIRS / 256; ++i) {
    int p = i * 256 + tid;
    int s = atomicAdd(&cur[eidx[p]], 1);
    tok_of[s] = p >> 1;
    slot_of[p] = s;
  }
}

// gather x rows (fp32) into slot-ordered bf16 Xg
__global__ void k_gather(const float* __restrict__ x, const int* __restrict__ tok_of,
                         unsigned short* __restrict__ Xg) {
  int s = blockIdx.x;
  int lane = threadIdx.x;
  int t = tok_of[s];
  const f32x4* xr = (const f32x4*)(x + (size_t)t * H_DIM);
  u16x4* orow = (u16x4*)(Xg + (size_t)s * H_DIM);
#pragma unroll
  for (int i = 0; i < H_DIM / 256; ++i) {
    f32x4 v = xr[i * 64 + lane];
    u16x4 o;
    o[0] = f2bf(v[0]); o[1] = f2bf(v[1]); o[2] = f2bf(v[2]); o[3] = f2bf(v[3]);
    orow[i * 64 + lane] = o;
  }
}

// in: [E][R][C] fp32 -> out: [E][C][R] bf16 (B^T layout), 64x64 tiles, wide stores.
__global__ __launch_bounds__(256) void k_transpose_cast(
    const float* __restrict__ in, unsigned short* __restrict__ out, int R, int C) {
  __shared__ unsigned short tile[64][72];
  int e  = blockIdx.z;
  int c0 = blockIdx.x * 64, r0 = blockIdx.y * 64;
  const float* ip = in + (size_t)e * R * C;
  unsigned short* op = out + (size_t)e * R * C;
  int tid = threadIdx.x;
  int tx = tid & 15, ty = tid >> 4;
#pragma unroll
  for (int i = 0; i < 4; ++i) {
    int r = ty + 16 * i;
    f32x4 v = *(const f32x4*)&ip[(size_t)(r0 + r) * C + c0 + tx * 4];
    u16x4 o;
    o[0] = f2bf(v[0]); o[1] = f2bf(v[1]); o[2] = f2bf(v[2]); o[3] = f2bf(v[3]);
    *(u16x4*)&tile[r][tx * 4] = o;
  }
  __syncthreads();
  int c  = tid & 63;
  int rc = (tid >> 6) * 16;
#pragma unroll
  for (int h = 0; h < 2; ++h) {
    u16x8 o;
#pragma unroll
    for (int j = 0; j < 8; ++j) o[j] = tile[rc + h * 8 + j][c];
    *(u16x8*)&op[(size_t)(c0 + c) * R + r0 + rc + h * 8] = o;
  }
}

// m97-exact 128x128-tile GEMM: 4 waves (2x2 of 64x64), BK=64, SINGLE-buffered
// 32 KB LDS -> multi-block residency (inter-block overlap is the pipeline).
// A [slots][KTOT] bf16, B^T [E][NDIM][KTOT] bf16, per-expert row segments.
// T2 swizzle (r2-verified, conflicts=0): linear LDS dest + permuted global
// source col + XOR'd ds_read. Balanced decode: nt inner, e mid, mt outermost.
template <int KTOT, int NT, int NSPLIT, bool GELU_OUT>
__global__ __launch_bounds__(256) void k_gemm(
    const unsigned short* __restrict__ A, const unsigned short* __restrict__ B,
    const float* __restrict__ bias, void* __restrict__ C,
    const int* __restrict__ counts, const int* __restrict__ offsets) {
  constexpr int NDIM = NT * 128;
  constexpr int KLEN = KTOT / NSPLIT;
  int l = blockIdx.x;
  int nt = l % NT;  l /= NT;
  int e  = l & 7;   l >>= 3;
  int part = l % NSPLIT;
  int mt = l / NSPLIT;
  int Me = counts[e];
  if (mt * 128 >= Me) return;
  int seg = offsets[e];

  __shared__ __align__(16) unsigned short Al[128 * 64];
  __shared__ __align__(16) unsigned short Bl[128 * 64];

  int tid  = threadIdx.x;
  int lane = tid & 63;
  int wave = tid >> 6;
  int wm = wave >> 1, wn = wave & 1;   // 2x2 waves, 64x64 each

  int sr   = tid >> 3;                               // staging row 0..31 per pass
  int scl  = (tid & 7) * 8;                          // linear LDS col (elems)
  int scs  = (((tid & 7) ^ (sr & 7)) * 8);           // swizzled global source col
  int rxor = (lane & 7) << 3;                        // read-side XOR (elems)

  f32x4 acc[4][4];
#pragma unroll
  for (int m = 0; m < 4; ++m)
#pragma unroll
    for (int n = 0; n < 4; ++n) acc[m][n] = (f32x4){0.f, 0.f, 0.f, 0.f};

  const unsigned short* Abase = A + (size_t)seg * KTOT;
  const unsigned short* Bbase = B + (size_t)e * NDIM * KTOT + (size_t)(nt * 128) * KTOT;
  const int kbeg = part * KLEN;

  for (int k0 = kbeg; k0 < kbeg + KLEN; k0 += 64) {
#pragma unroll
    for (int j = 0; j < 4; ++j) {
      int row = j * 32 + sr;
      int r = mt * 128 + row;
      r = (r < Me) ? r : (Me - 1);     // clamp (dup last row; stores predicated)
      const unsigned short* gp = Abase + (size_t)r * KTOT + k0 + scs;
      __builtin_amdgcn_global_load_lds(
          (__attribute__((address_space(1))) void*)gp,
          (__attribute__((address_space(3))) void*)&Al[row * 64 + scl], 16, 0, 0);
    }
#pragma unroll
    for (int j = 0; j < 4; ++j) {
      int row = j * 32 + sr;
      const unsigned short* gp = Bbase + (size_t)row * KTOT + k0 + scs;
      __builtin_amdgcn_global_load_lds(
          (__attribute__((address_space(1))) void*)gp,
          (__attribute__((address_space(3))) void*)&Bl[row * 64 + scl], 16, 0, 0);
    }
    __syncthreads();

#pragma unroll
    for (int kk = 0; kk < 2; ++kk) {
      int ko = kk * 32 + (lane >> 4) * 8;
      s16x8 af[4], bfr[4];
#pragma unroll
      for (int m = 0; m < 4; ++m) {
        int row = wm * 64 + m * 16 + (lane & 15);
        u32x4 v = *(const u32x4*)&Al[(row * 64 + ko) ^ rxor];
        af[m] = __builtin_bit_cast(s16x8, v);
      }
#pragma unroll
      for (int n = 0; n < 4; ++n) {
        int row = wn * 64 + n * 16 + (lane & 15);
        u32x4 v = *(const u32x4*)&Bl[(row * 64 + ko) ^ rxor];
        bfr[n] = __builtin_bit_cast(s16x8, v);
      }
#pragma unroll
      for (int m = 0; m < 4; ++m)
#pragma unroll
        for (int n = 0; n < 4; ++n)
          acc[m][n] = __builtin_amdgcn_mfma_f32_16x16x32_bf16(af[m], bfr[n], acc[m][n], 0, 0, 0);
    }
    __syncthreads();
  }

  // epilogue: C/D layout col = lane&15, row = (lane>>4)*4 + reg
  int rbase = mt * 128 + wm * 64;
  int cbase = nt * 128 + wn * 64;
#pragma unroll
  for (int m = 0; m < 4; ++m) {
#pragma unroll
    for (int n = 0; n < 4; ++n) {
      int col = cbase + n * 16 + (lane & 15);
      float bv = GELU_OUT ? bias[e * NDIM + col] : 0.f;
#pragma unroll
      for (int r = 0; r < 4; ++r) {
        int row = rbase + m * 16 + (lane >> 4) * 4 + r;
        if (row < Me) {
          float v = acc[m][n][r] + bv;
          size_t idx = ((size_t)part * PAIRS + seg + row) * NDIM + col;
          if constexpr (GELU_OUT) {
            ((unsigned short*)C)[idx] = f2bf(gelu_fast(v));
          } else {
            ((float*)C)[idx] = v;   // raw partial; bias added in combine
          }
        }
      }
    }
  }
}

// out[t] = w0*(sum_p P[p][s0] + b2[e0]) + w1*(sum_p P[p][s1] + b2[e1])
template <int NSPLIT>
__global__ void k_combine(const float* __restrict__ P, const int* __restrict__ slot_of,
                          const int* __restrict__ eidx, const float* __restrict__ ew,
                          const float* __restrict__ b2, float* __restrict__ out) {
  int t = blockIdx.x;
  int i = threadIdx.x;  // 192 threads * float4 = 768
  int s0 = slot_of[2 * t], s1 = slot_of[2 * t + 1];
  int e0 = eidx[2 * t],    e1 = eidx[2 * t + 1];
  float w0 = ew[2 * t], w1 = ew[2 * t + 1];
  f32x4 a = *(const f32x4*)&b2[e0 * H_DIM + i * 4];
  f32x4 c = *(const f32x4*)&b2[e1 * H_DIM + i * 4];
#pragma unroll
  for (int p = 0; p < NSPLIT; ++p) {
    f32x4 va = *(const f32x4*)&P[((size_t)p * PAIRS + s0) * H_DIM + i * 4];
    f32x4 vb = *(const f32x4*)&P[((size_t)p * PAIRS + s1) * H_DIM + i * 4];
    a[0] += va[0]; a[1] += va[1]; a[2] += va[2]; a[3] += va[3];
    c[0] += vb[0]; c[1] += vb[1]; c[2] += vb[2]; c[3] += vb[3];
  }
  f32x4 o;
  o[0] = w0 * a[0] + w1 * c[0];
  o[1] = w0 * a[1] + w1 * c[1];
  o[2] = w0 * a[2] + w1 * c[2];
  o[3] = w0 * a[3] + w1 * c[3];
  ((f32x4*)(out + (size_t)t * H_DIM))[i] = o;
}

extern "C" void kernel_launch(void* const* d_in, const int* in_sizes, int n_in,
                              void* d_out, int out_size, void* d_ws, size_t ws_size,
                              hipStream_t stream) {
  (void)in_sizes; (void)n_in; (void)out_size;
  const float* x  = (const float*)d_in[0];
  const float* Wg = (const float*)d_in[1];
  const float* bg = (const float*)d_in[2];
  const float* W1 = (const float*)d_in[3];
  const float* b1 = (const float*)d_in[4];
  const float* W2 = (const float*)d_in[5];
  const float* b2 = (const float*)d_in[6];
  float* out = (float*)d_out;

  char* w = (char*)d_ws;
  size_t off = 0;
  auto take = [&](size_t n) { void* p = w + off; off = (off + n + 255) & ~(size_t)255; return p; };
  int*   ctrl    = (int*)  take(64 * sizeof(int));   // [0..7] counts, [8..15] offsets
  int*   eidx    = (int*)  take(PAIRS * sizeof(int));
  float* ew      = (float*)take(PAIRS * sizeof(float));
  int*   slot_of = (int*)  take(PAIRS * sizeof(int));
  int*   tok_of  = (int*)  take(PAIRS * sizeof(int));
  unsigned short* Xg   = (unsigned short*)take((size_t)PAIRS * H_DIM * 2);
  unsigned short* Wb   = (unsigned short*)take((size_t)E_NUM * H_DIM * DFF * 2);  // W1b then W2b
  unsigned short* Hmid = (unsigned short*)take((size_t)PAIRS * DFF * 2);
  size_t p_off = off;
  float* P = (float*)(w + p_off);
  bool split4 = (p_off + (size_t)4 * PAIRS * H_DIM * sizeof(float)) <= ws_size;
  if (p_off + (size_t)PAIRS * H_DIM * sizeof(float) > ws_size) return;

  int* counts  = ctrl;
  int* offsets = ctrl + 8;

  k_route<<<T_NUM / 4, 256, 0, stream>>>(x, Wg, bg, eidx, ew);
  k_build<<<1, 256, 0, stream>>>(eidx, counts, offsets, tok_of, slot_of);
  k_gather<<<PAIRS, 64, 0, stream>>>(x, tok_of, Xg);

  // W1 [E][768][3072] -> Wb [E][3072][768] bf16
  k_transpose_cast<<<dim3(DFF / 64, H_DIM / 64, E_NUM), 256, 0, stream>>>(W1, Wb, H_DIM, DFF);
  // GEMM1: 24 nt * 8 e * 16 mt = 3072 blocks (active ~768 = 3/CU)
  k_gemm<H_DIM, DFF / 128, 1, true><<<(DFF / 128) * E_NUM * 16, 256, 0, stream>>>(
      Xg, Wb, b1, Hmid, counts, offsets);

  // W2 [E][3072][768] -> Wb [E][768][3072] bf16 (reuse; stream order serializes)
  k_transpose_cast<<<dim3(H_DIM / 64, DFF / 64, E_NUM), 256, 0, stream>>>(W2, Wb, DFF, H_DIM);

  if (split4) {
    // GEMM2: 6 nt * 8 e * 4 part * 16 mt = 3072 blocks (active ~768 = 3/CU)
    k_gemm<DFF, H_DIM / 128, 4, false><<<(H_DIM / 128) * E_NUM * 4 * 16, 256, 0, stream>>>(
        Hmid, Wb, b2, P, counts, offsets);
    k_combine<4><<<T_NUM, 192, 0, stream>>>(P, slot_of, eidx, ew, b2, out);
  } else {
    k_gemm<DFF, H_DIM / 128, 1, false><<<(H_DIM / 128) * E_NUM * 16, 256, 0, stream>>>(
        Hmid, Wb, b2, P, counts, offsets);
    k_combine<1><<<T_NUM, 192, 0, stream>>>(P, slot_of, eidx, ew, b2, out);
  }
}

// Round 6
// 170.143 us; speedup vs baseline: 1.3992x; 1.0204x over previous
//
#include <hip/hip_runtime.h>
#include <hip/hip_bf16.h>
#include <math.h>

#define H_DIM 768
#define E_NUM 8
#define DFF   3072
#define T_NUM 2048
#define PAIRS 4096   // T_NUM * top_k(=2), constant by construction

typedef __attribute__((ext_vector_type(8))) short          s16x8;
typedef __attribute__((ext_vector_type(4))) float          f32x4;
typedef __attribute__((ext_vector_type(4))) unsigned int   u32x4;
typedef __attribute__((ext_vector_type(4))) unsigned short u16x4;
typedef __attribute__((ext_vector_type(8))) unsigned short u16x8;

__device__ __forceinline__ unsigned short f2bf(float f) {
  unsigned int u = __builtin_bit_cast(unsigned int, f);
  u += 0x7FFFu + ((u >> 16) & 1u);     // round-to-nearest-even
  return (unsigned short)(u >> 16);
}

// branchless tanh-form GELU: x * sigmoid(1.59577*(x + 0.044715 x^3))
// exp2 arg folded; max |err vs erf-GELU| ~3e-4 (<< bf16 noise, threshold 5.7e-2)
__device__ __forceinline__ float gelu_fast(float x) {
  float t = x * x;
  float a = __builtin_fmaf(t, -0.10294221f, -2.3022082f);
  float w;
  asm("v_exp_f32 %0, %1" : "=v"(w) : "v"(x * a));
  float r;
  float d = 1.0f + w;
  asm("v_rcp_f32 %0, %1" : "=v"(r) : "v"(d));
  return x * r;
}

// ---------------- routing: logits -> softmax -> top2 -> renorm weights ---------------
// NO global atomics (r4 lesson: 4096 device-scope atomics on one line = 54 us).
__global__ __launch_bounds__(256) void k_route(
    const float* __restrict__ x, const float* __restrict__ Wg,
    const float* __restrict__ bg, int* __restrict__ eidx, float* __restrict__ ew) {
  int wave = threadIdx.x >> 6, lane = threadIdx.x & 63;
  int t = blockIdx.x * 4 + wave;
  const float* xr = x + (size_t)t * H_DIM;
  float acc[E_NUM];
#pragma unroll
  for (int e = 0; e < E_NUM; ++e) acc[e] = 0.f;
#pragma unroll
  for (int i = 0; i < H_DIM / 64; ++i) {
    int h = i * 64 + lane;
    float xv = xr[h];
    f32x4 w0 = *(const f32x4*)&Wg[h * 8];
    f32x4 w1 = *(const f32x4*)&Wg[h * 8 + 4];
    acc[0] += xv * w0[0]; acc[1] += xv * w0[1];
    acc[2] += xv * w0[2]; acc[3] += xv * w0[3];
    acc[4] += xv * w1[0]; acc[5] += xv * w1[1];
    acc[6] += xv * w1[2]; acc[7] += xv * w1[3];
  }
#pragma unroll
  for (int e = 0; e < E_NUM; ++e) {
#pragma unroll
    for (int off = 32; off > 0; off >>= 1) acc[e] += __shfl_xor(acc[e], off);
  }
  if (lane == 0) {
    float l[E_NUM];
#pragma unroll
    for (int e = 0; e < E_NUM; ++e) l[e] = acc[e] + bg[e];
    int i0 = 0;
#pragma unroll
    for (int e = 1; e < E_NUM; ++e) if (l[e] > l[i0]) i0 = e;
    int i1 = (i0 == 0) ? 1 : 0;
#pragma unroll
    for (int e = 0; e < E_NUM; ++e) if (e != i0 && l[e] > l[i1]) i1 = e;
    float d  = expf(l[i1] - l[i0]);
    eidx[2 * t]     = i0;
    eidx[2 * t + 1] = i1;
    ew[2 * t]       = 1.f / (1.f + d);
    ew[2 * t + 1]   = d / (1.f + d);
  }
}

// Single block: LDS histogram -> prefix -> LDS-atomic scatter.
__global__ __launch_bounds__(256) void k_build(
    const int* __restrict__ eidx, int* __restrict__ counts, int* __restrict__ offsets,
    int* __restrict__ tok_of, int* __restrict__ slot_of) {
  __shared__ int cnt[E_NUM];
  __shared__ int cur[E_NUM];
  int tid = threadIdx.x;
  if (tid < E_NUM) cnt[tid] = 0;
  __syncthreads();
#pragma unroll
  for (int i = 0; i < PAIRS / 256; ++i)
    atomicAdd(&cnt[eidx[i * 256 + tid]], 1);
  __syncthreads();
  if (tid == 0) {
    int s = 0;
    for (int e = 0; e < E_NUM; ++e) { cur[e] = s; s += cnt[e]; }
  }
  __syncthreads();
  if (tid < E_NUM) { counts[tid] = cnt[tid]; offsets[tid] = cur[tid]; }
#pragma unroll
  for (int i = 0; i < PAIRS / 256; ++i) {
    int p = i * 256 + tid;
    int s = atomicAdd(&cur[eidx[p]], 1);
    tok_of[s] = p >> 1;
    slot_of[p] = s;
  }
}

// gather x rows (fp32) into slot-ordered bf16 Xg
__global__ void k_gather(const float* __restrict__ x, const int* __restrict__ tok_of,
                         unsigned short* __restrict__ Xg) {
  int s = blockIdx.x;
  int lane = threadIdx.x;
  int t = tok_of[s];
  const f32x4* xr = (const f32x4*)(x + (size_t)t * H_DIM);
  u16x4* orow = (u16x4*)(Xg + (size_t)s * H_DIM);
#pragma unroll
  for (int i = 0; i < H_DIM / 256; ++i) {
    f32x4 v = xr[i * 64 + lane];
    u16x4 o;
    o[0] = f2bf(v[0]); o[1] = f2bf(v[1]); o[2] = f2bf(v[2]); o[3] = f2bf(v[3]);
    orow[i * 64 + lane] = o;
  }
}

// in: [E][R][C] fp32 -> out: [E][C][R] bf16 (B^T layout), 64x64 tiles, wide stores.
__global__ __launch_bounds__(256) void k_transpose_cast(
    const float* __restrict__ in, unsigned short* __restrict__ out, int R, int C) {
  __shared__ unsigned short tile[64][72];
  int e  = blockIdx.z;
  int c0 = blockIdx.x * 64, r0 = blockIdx.y * 64;
  const float* ip = in + (size_t)e * R * C;
  unsigned short* op = out + (size_t)e * R * C;
  int tid = threadIdx.x;
  int tx = tid & 15, ty = tid >> 4;
#pragma unroll
  for (int i = 0; i < 4; ++i) {
    int r = ty + 16 * i;
    f32x4 v = *(const f32x4*)&ip[(size_t)(r0 + r) * C + c0 + tx * 4];
    u16x4 o;
    o[0] = f2bf(v[0]); o[1] = f2bf(v[1]); o[2] = f2bf(v[2]); o[3] = f2bf(v[3]);
    *(u16x4*)&tile[r][tx * 4] = o;
  }
  __syncthreads();
  int c  = tid & 63;
  int rc = (tid >> 6) * 16;
#pragma unroll
  for (int h = 0; h < 2; ++h) {
    u16x8 o;
#pragma unroll
    for (int j = 0; j < 8; ++j) o[j] = tile[rc + h * 8 + j][c];
    *(u16x8*)&op[(size_t)(c0 + c) * R + r0 + rc + h * 8] = o;
  }
}

// 128x128-tile GEMM, 4 waves (2x2 of 64x64), BK=64, DOUBLE-buffered LDS (64 KB)
// with T4 counted vmcnt: each thread issues 8 global_load_lds per stage; with 2
// tiles in flight, vmcnt(8) retires the current tile while next-tile loads stay
// in flight across the barrier (never drain to 0 in the main loop).
// T2 swizzle (r2-verified, conflicts=0): linear LDS dest + permuted global
// source col + XOR'd ds_read. Decode: nt inner, e mid, mt outer (dead tiles last).
template <int KTOT, int NT, int NSPLIT, int MT_MAX, bool GELU_OUT>
__global__ __launch_bounds__(256) void k_gemm(
    const unsigned short* __restrict__ A, const unsigned short* __restrict__ B,
    const float* __restrict__ bias, void* __restrict__ C,
    const int* __restrict__ counts, const int* __restrict__ offsets) {
  constexpr int NDIM  = NT * 128;
  constexpr int KLEN  = KTOT / NSPLIT;
  constexpr int NSTEP = KLEN / 64;
  int l = blockIdx.x;
  int nt = l % NT;  l /= NT;
  int e  = l & 7;   l >>= 3;
  int part = l % NSPLIT;
  int mt = l / NSPLIT;
  int Me = counts[e];
  if (mt * 128 >= Me) return;
  int seg = offsets[e];

  __shared__ __align__(16) unsigned short Al[2][128 * 64];
  __shared__ __align__(16) unsigned short Bl[2][128 * 64];

  int tid  = threadIdx.x;
  int lane = tid & 63;
  int wave = tid >> 6;
  int wm = wave >> 1, wn = wave & 1;   // 2x2 waves, 64x64 each

  int sr   = tid >> 3;                               // staging row 0..31 per pass
  int scl  = (tid & 7) * 8;                          // linear LDS col (elems)
  int scs  = (((tid & 7) ^ (sr & 7)) * 8);           // swizzled global source col
  int rxor = (lane & 7) << 3;                        // read-side XOR (elems)

  f32x4 acc[4][4];
#pragma unroll
  for (int m = 0; m < 4; ++m)
#pragma unroll
    for (int n = 0; n < 4; ++n) acc[m][n] = (f32x4){0.f, 0.f, 0.f, 0.f};

  const unsigned short* Abase = A + (size_t)seg * KTOT;
  const unsigned short* Bbase = B + (size_t)e * NDIM * KTOT + (size_t)(nt * 128) * KTOT;
  const int kbeg = part * KLEN;

  auto stage = [&](int bb, int k0) {   // 8 global_load_lds per thread
#pragma unroll
    for (int j = 0; j < 4; ++j) {
      int row = j * 32 + sr;
      int r = mt * 128 + row;
      r = (r < Me) ? r : (Me - 1);     // clamp (dup last row; stores predicated)
      const unsigned short* gp = Abase + (size_t)r * KTOT + k0 + scs;
      __builtin_amdgcn_global_load_lds(
          (__attribute__((address_space(1))) void*)gp,
          (__attribute__((address_space(3))) void*)&Al[bb][row * 64 + scl], 16, 0, 0);
    }
#pragma unroll
    for (int j = 0; j < 4; ++j) {
      int row = j * 32 + sr;
      const unsigned short* gp = Bbase + (size_t)row * KTOT + k0 + scs;
      __builtin_amdgcn_global_load_lds(
          (__attribute__((address_space(1))) void*)gp,
          (__attribute__((address_space(3))) void*)&Bl[bb][row * 64 + scl], 16, 0, 0);
    }
  };

  auto compute = [&](int bb) {
#pragma unroll
    for (int kk = 0; kk < 2; ++kk) {
      int ko = kk * 32 + (lane >> 4) * 8;
      s16x8 af[4], bfr[4];
#pragma unroll
      for (int m = 0; m < 4; ++m) {
        int row = wm * 64 + m * 16 + (lane & 15);
        u32x4 v = *(const u32x4*)&Al[bb][(row * 64 + ko) ^ rxor];
        af[m] = __builtin_bit_cast(s16x8, v);
      }
#pragma unroll
      for (int n = 0; n < 4; ++n) {
        int row = wn * 64 + n * 16 + (lane & 15);
        u32x4 v = *(const u32x4*)&Bl[bb][(row * 64 + ko) ^ rxor];
        bfr[n] = __builtin_bit_cast(s16x8, v);
      }
#pragma unroll
      for (int m = 0; m < 4; ++m)
#pragma unroll
        for (int n = 0; n < 4; ++n)
          acc[m][n] = __builtin_amdgcn_mfma_f32_16x16x32_bf16(af[m], bfr[n], acc[m][n], 0, 0, 0);
    }
  };

  stage(0, kbeg);
  stage(1, kbeg + 64);
  int cur = 0;
#pragma unroll
  for (int s = 0; s < NSTEP; ++s) {
    // retire exactly the current tile's 8 loads; keep next tile's in flight
    if (s + 1 < NSTEP) asm volatile("s_waitcnt vmcnt(8)" ::: "memory");
    else               asm volatile("s_waitcnt vmcnt(0)" ::: "memory");
    __builtin_amdgcn_s_barrier();      // all waves' cur-tile loads landed
    compute(cur);                      // ds_read + MFMA (compiler handles lgkm)
    if (s + 2 < NSTEP) {
      __builtin_amdgcn_s_barrier();    // all waves done READING cur
      stage(cur, kbeg + (s + 2) * 64); // overwrite cur with tile s+2
    }
    cur ^= 1;
  }

  // epilogue: C/D layout col = lane&15, row = (lane>>4)*4 + reg
  int rbase = mt * 128 + wm * 64;
  int cbase = nt * 128 + wn * 64;
#pragma unroll
  for (int m = 0; m < 4; ++m) {
#pragma unroll
    for (int n = 0; n < 4; ++n) {
      int col = cbase + n * 16 + (lane & 15);
      float bv = GELU_OUT ? bias[e * NDIM + col] : 0.f;
#pragma unroll
      for (int r = 0; r < 4; ++r) {
        int row = rbase + m * 16 + (lane >> 4) * 4 + r;
        if (row < Me) {
          float v = acc[m][n][r] + bv;
          size_t idx = ((size_t)part * PAIRS + seg + row) * NDIM + col;
          if constexpr (GELU_OUT) {
            ((unsigned short*)C)[idx] = f2bf(gelu_fast(v));
          } else {
            ((float*)C)[idx] = v;   // raw partial; bias added in combine
          }
        }
      }
    }
  }
}

// out[t] = w0*(sum_p P[p][s0] + b2[e0]) + w1*(sum_p P[p][s1] + b2[e1])
template <int NSPLIT>
__global__ void k_combine(const float* __restrict__ P, const int* __restrict__ slot_of,
                          const int* __restrict__ eidx, const float* __restrict__ ew,
                          const float* __restrict__ b2, float* __restrict__ out) {
  int t = blockIdx.x;
  int i = threadIdx.x;  // 192 threads * float4 = 768
  int s0 = slot_of[2 * t], s1 = slot_of[2 * t + 1];
  int e0 = eidx[2 * t],    e1 = eidx[2 * t + 1];
  float w0 = ew[2 * t], w1 = ew[2 * t + 1];
  f32x4 a = *(const f32x4*)&b2[e0 * H_DIM + i * 4];
  f32x4 c = *(const f32x4*)&b2[e1 * H_DIM + i * 4];
#pragma unroll
  for (int p = 0; p < NSPLIT; ++p) {
    f32x4 va = *(const f32x4*)&P[((size_t)p * PAIRS + s0) * H_DIM + i * 4];
    f32x4 vb = *(const f32x4*)&P[((size_t)p * PAIRS + s1) * H_DIM + i * 4];
    a[0] += va[0]; a[1] += va[1]; a[2] += va[2]; a[3] += va[3];
    c[0] += vb[0]; c[1] += vb[1]; c[2] += vb[2]; c[3] += vb[3];
  }
  f32x4 o;
  o[0] = w0 * a[0] + w1 * c[0];
  o[1] = w0 * a[1] + w1 * c[1];
  o[2] = w0 * a[2] + w1 * c[2];
  o[3] = w0 * a[3] + w1 * c[3];
  ((f32x4*)(out + (size_t)t * H_DIM))[i] = o;
}

extern "C" void kernel_launch(void* const* d_in, const int* in_sizes, int n_in,
                              void* d_out, int out_size, void* d_ws, size_t ws_size,
                              hipStream_t stream) {
  (void)in_sizes; (void)n_in; (void)out_size;
  const float* x  = (const float*)d_in[0];
  const float* Wg = (const float*)d_in[1];
  const float* bg = (const float*)d_in[2];
  const float* W1 = (const float*)d_in[3];
  const float* b1 = (const float*)d_in[4];
  const float* W2 = (const float*)d_in[5];
  const float* b2 = (const float*)d_in[6];
  float* out = (float*)d_out;

  char* w = (char*)d_ws;
  size_t off = 0;
  auto take = [&](size_t n) { void* p = w + off; off = (off + n + 255) & ~(size_t)255; return p; };
  int*   ctrl    = (int*)  take(64 * sizeof(int));   // [0..7] counts, [8..15] offsets
  int*   eidx    = (int*)  take(PAIRS * sizeof(int));
  float* ew      = (float*)take(PAIRS * sizeof(float));
  int*   slot_of = (int*)  take(PAIRS * sizeof(int));
  int*   tok_of  = (int*)  take(PAIRS * sizeof(int));
  unsigned short* Xg   = (unsigned short*)take((size_t)PAIRS * H_DIM * 2);
  unsigned short* Wb   = (unsigned short*)take((size_t)E_NUM * H_DIM * DFF * 2);  // W1b then W2b
  unsigned short* Hmid = (unsigned short*)take((size_t)PAIRS * DFF * 2);
  size_t p_off = off;
  float* P = (float*)(w + p_off);
  bool split4 = (p_off + (size_t)4 * PAIRS * H_DIM * sizeof(float)) <= ws_size;
  if (p_off + (size_t)PAIRS * H_DIM * sizeof(float) > ws_size) return;

  int* counts  = ctrl;
  int* offsets = ctrl + 8;

  k_route<<<T_NUM / 4, 256, 0, stream>>>(x, Wg, bg, eidx, ew);
  k_build<<<1, 256, 0, stream>>>(eidx, counts, offsets, tok_of, slot_of);
  k_gather<<<PAIRS, 64, 0, stream>>>(x, tok_of, Xg);

  // W1 [E][768][3072] -> Wb [E][3072][768] bf16
  k_transpose_cast<<<dim3(DFF / 64, H_DIM / 64, E_NUM), 256, 0, stream>>>(W1, Wb, H_DIM, DFF);
  // GEMM1: 24 nt * 8 e * 8 mt = 1536 blocks (active ~768 = 3/CU)
  k_gemm<H_DIM, DFF / 128, 1, 8, true><<<(DFF / 128) * E_NUM * 8, 256, 0, stream>>>(
      Xg, Wb, b1, Hmid, counts, offsets);

  // W2 [E][3072][768] -> Wb [E][768][3072] bf16 (reuse; stream order serializes)
  k_transpose_cast<<<dim3(H_DIM / 64, DFF / 64, E_NUM), 256, 0, stream>>>(W2, Wb, DFF, H_DIM);

  if (split4) {
    // GEMM2: 6 nt * 8 e * 4 part * 8 mt = 1536 blocks (active ~768 = 3/CU)
    k_gemm<DFF, H_DIM / 128, 4, 8, false><<<(H_DIM / 128) * E_NUM * 4 * 8, 256, 0, stream>>>(
        Hmid, Wb, b2, P, counts, offsets);
    k_combine<4><<<T_NUM, 192, 0, stream>>>(P, slot_of, eidx, ew, b2, out);
  } else {
    k_gemm<DFF, H_DIM / 128, 1, 8, false><<<(H_DIM / 128) * E_NUM * 8, 256, 0, stream>>>(
        Hmid, Wb, b2, P, counts, offsets);
    k_combine<1><<<T_NUM, 192, 0, stream>>>(P, slot_of, eidx, ew, b2, out);
  }
}

// Round 7
// 169.479 us; speedup vs baseline: 1.4047x; 1.0039x over previous
//
#include <hip/hip_runtime.h>
#include <hip/hip_bf16.h>
#include <math.h>

#define H_DIM 768
#define E_NUM 8
#define DFF   3072
#define T_NUM 2048
#define PAIRS 4096   // T_NUM * top_k(=2), constant by construction

typedef __attribute__((ext_vector_type(8))) short          s16x8;
typedef __attribute__((ext_vector_type(4))) float          f32x4;
typedef __attribute__((ext_vector_type(4))) unsigned int   u32x4;
typedef __attribute__((ext_vector_type(4))) unsigned short u16x4;
typedef __attribute__((ext_vector_type(8))) unsigned short u16x8;

__device__ __forceinline__ unsigned short f2bf(float f) {
  unsigned int u = __builtin_bit_cast(unsigned int, f);
  u += 0x7FFFu + ((u >> 16) & 1u);     // round-to-nearest-even
  return (unsigned short)(u >> 16);
}

__device__ __forceinline__ float bf2f(unsigned short v) {
  unsigned int u = ((unsigned int)v) << 16;
  return __builtin_bit_cast(float, u);
}

// branchless tanh-form GELU: x * sigmoid(1.59577*(x + 0.044715 x^3))
// exp2 arg folded; max |err vs erf-GELU| ~3e-4 (<< bf16 noise, threshold 5.7e-2)
__device__ __forceinline__ float gelu_fast(float x) {
  float t = x * x;
  float a = __builtin_fmaf(t, -0.10294221f, -2.3022082f);
  float w;
  asm("v_exp_f32 %0, %1" : "=v"(w) : "v"(x * a));
  float r;
  float d = 1.0f + w;
  asm("v_rcp_f32 %0, %1" : "=v"(r) : "v"(d));
  return x * r;
}

// ---------------- routing: logits -> softmax -> top2 -> renorm weights ---------------
// NO global atomics (r4 lesson: 4096 device-scope atomics on one line = 54 us).
__global__ __launch_bounds__(256) void k_route(
    const float* __restrict__ x, const float* __restrict__ Wg,
    const float* __restrict__ bg, int* __restrict__ eidx, float* __restrict__ ew) {
  int wave = threadIdx.x >> 6, lane = threadIdx.x & 63;
  int t = blockIdx.x * 4 + wave;
  const float* xr = x + (size_t)t * H_DIM;
  float acc[E_NUM];
#pragma unroll
  for (int e = 0; e < E_NUM; ++e) acc[e] = 0.f;
#pragma unroll
  for (int i = 0; i < H_DIM / 64; ++i) {
    int h = i * 64 + lane;
    float xv = xr[h];
    f32x4 w0 = *(const f32x4*)&Wg[h * 8];
    f32x4 w1 = *(const f32x4*)&Wg[h * 8 + 4];
    acc[0] += xv * w0[0]; acc[1] += xv * w0[1];
    acc[2] += xv * w0[2]; acc[3] += xv * w0[3];
    acc[4] += xv * w1[0]; acc[5] += xv * w1[1];
    acc[6] += xv * w1[2]; acc[7] += xv * w1[3];
  }
#pragma unroll
  for (int e = 0; e < E_NUM; ++e) {
#pragma unroll
    for (int off = 32; off > 0; off >>= 1) acc[e] += __shfl_xor(acc[e], off);
  }
  if (lane == 0) {
    float l[E_NUM];
#pragma unroll
    for (int e = 0; e < E_NUM; ++e) l[e] = acc[e] + bg[e];
    int i0 = 0;
#pragma unroll
    for (int e = 1; e < E_NUM; ++e) if (l[e] > l[i0]) i0 = e;
    int i1 = (i0 == 0) ? 1 : 0;
#pragma unroll
    for (int e = 0; e < E_NUM; ++e) if (e != i0 && l[e] > l[i1]) i1 = e;
    float d  = expf(l[i1] - l[i0]);
    eidx[2 * t]     = i0;
    eidx[2 * t + 1] = i1;
    ew[2 * t]       = 1.f / (1.f + d);
    ew[2 * t + 1]   = d / (1.f + d);
  }
}

// Single block: LDS histogram -> prefix -> LDS-atomic scatter.
__global__ __launch_bounds__(256) void k_build(
    const int* __restrict__ eidx, int* __restrict__ counts, int* __restrict__ offsets,
    int* __restrict__ tok_of, int* __restrict__ slot_of) {
  __shared__ int cnt[E_NUM];
  __shared__ int cur[E_NUM];
  int tid = threadIdx.x;
  if (tid < E_NUM) cnt[tid] = 0;
  __syncthreads();
#pragma unroll
  for (int i = 0; i < PAIRS / 256; ++i)
    atomicAdd(&cnt[eidx[i * 256 + tid]], 1);
  __syncthreads();
  if (tid == 0) {
    int s = 0;
    for (int e = 0; e < E_NUM; ++e) { cur[e] = s; s += cnt[e]; }
  }
  __syncthreads();
  if (tid < E_NUM) { counts[tid] = cnt[tid]; offsets[tid] = cur[tid]; }
#pragma unroll
  for (int i = 0; i < PAIRS / 256; ++i) {
    int p = i * 256 + tid;
    int s = atomicAdd(&cur[eidx[p]], 1);
    tok_of[s] = p >> 1;
    slot_of[p] = s;
  }
}

// gather x rows (fp32) into slot-ordered bf16 Xg
__global__ void k_gather(const float* __restrict__ x, const int* __restrict__ tok_of,
                         unsigned short* __restrict__ Xg) {
  int s = blockIdx.x;
  int lane = threadIdx.x;
  int t = tok_of[s];
  const f32x4* xr = (const f32x4*)(x + (size_t)t * H_DIM);
  u16x4* orow = (u16x4*)(Xg + (size_t)s * H_DIM);
#pragma unroll
  for (int i = 0; i < H_DIM / 256; ++i) {
    f32x4 v = xr[i * 64 + lane];
    u16x4 o;
    o[0] = f2bf(v[0]); o[1] = f2bf(v[1]); o[2] = f2bf(v[2]); o[3] = f2bf(v[3]);
    orow[i * 64 + lane] = o;
  }
}

// in: [E][R][C] fp32 -> out: [E][C][R] bf16 (B^T layout), 64x64 tiles, wide stores.
__global__ __launch_bounds__(256) void k_transpose_cast(
    const float* __restrict__ in, unsigned short* __restrict__ out, int R, int C) {
  __shared__ unsigned short tile[64][72];
  int e  = blockIdx.z;
  int c0 = blockIdx.x * 64, r0 = blockIdx.y * 64;
  const float* ip = in + (size_t)e * R * C;
  unsigned short* op = out + (size_t)e * R * C;
  int tid = threadIdx.x;
  int tx = tid & 15, ty = tid >> 4;
#pragma unroll
  for (int i = 0; i < 4; ++i) {
    int r = ty + 16 * i;
    f32x4 v = *(const f32x4*)&ip[(size_t)(r0 + r) * C + c0 + tx * 4];
    u16x4 o;
    o[0] = f2bf(v[0]); o[1] = f2bf(v[1]); o[2] = f2bf(v[2]); o[3] = f2bf(v[3]);
    *(u16x4*)&tile[r][tx * 4] = o;
  }
  __syncthreads();
  int c  = tid & 63;
  int rc = (tid >> 6) * 16;
#pragma unroll
  for (int h = 0; h < 2; ++h) {
    u16x8 o;
#pragma unroll
    for (int j = 0; j < 8; ++j) o[j] = tile[rc + h * 8 + j][c];
    *(u16x8*)&op[(size_t)(c0 + c) * R + r0 + rc + h * 8] = o;
  }
}

// 256x128-tile GEMM, 8 waves (4m x 2n of 64x64 each), BK=64, double-buffered
// 96 KB LDS (1 block/CU, 2 waves/SIMD). Counted vmcnt(6): 6 global_load_lds per
// thread per tile, depth-2 prefetch; the 256-MFMA compute phase (~700 cy) covers
// the load latency. T2 swizzle (conflicts=0 verified r2-r6): linear LDS dest +
// permuted global source col + XOR'd ds_read ((row&7) == (lane&7) on all reads).
// GELU_OUT: gelu -> bf16 Hmid. Else: bf16 split-K partials (bias in combine).
template <int KTOT, int NT, int NSPLIT, int MT_MAX, bool GELU_OUT>
__global__ __launch_bounds__(512) void k_gemm(
    const unsigned short* __restrict__ A, const unsigned short* __restrict__ B,
    const float* __restrict__ bias, void* __restrict__ C,
    const int* __restrict__ counts, const int* __restrict__ offsets) {
  constexpr int NDIM  = NT * 128;
  constexpr int KLEN  = KTOT / NSPLIT;
  constexpr int NSTEP = KLEN / 64;
  int l = blockIdx.x;
  int nt = l % NT;  l /= NT;
  int e  = l & 7;   l >>= 3;
  int part = l % NSPLIT;
  int mt = l / NSPLIT;
  int Me = counts[e];
  if (mt * 256 >= Me) return;
  int seg = offsets[e];

  __shared__ __align__(16) unsigned short Al[2][256 * 64];
  __shared__ __align__(16) unsigned short Bl[2][128 * 64];

  int tid  = threadIdx.x;
  int lane = tid & 63;
  int wave = tid >> 6;
  int wm = wave >> 1, wn = wave & 1;   // 4m x 2n waves, 64x64 each

  int sr   = tid >> 3;                               // staging row 0..63 per pass
  int scl  = (tid & 7) * 8;                          // linear LDS col (elems)
  int scs  = (((tid & 7) ^ (sr & 7)) * 8);           // swizzled global source col
  int rxor = (lane & 7) << 3;                        // read-side XOR (elems)

  f32x4 acc[4][4];
#pragma unroll
  for (int m = 0; m < 4; ++m)
#pragma unroll
    for (int n = 0; n < 4; ++n) acc[m][n] = (f32x4){0.f, 0.f, 0.f, 0.f};

  const unsigned short* Abase = A + (size_t)seg * KTOT;
  const unsigned short* Bbase = B + (size_t)e * NDIM * KTOT + (size_t)(nt * 128) * KTOT;
  const int kbeg = part * KLEN;

  auto stage = [&](int bb, int k0) {   // 6 global_load_lds per thread
#pragma unroll
    for (int j = 0; j < 4; ++j) {      // A: 256 rows in 4 passes of 64
      int row = j * 64 + sr;
      int r = mt * 256 + row;
      r = (r < Me) ? r : (Me - 1);     // clamp (dup last row; stores predicated)
      const unsigned short* gp = Abase + (size_t)r * KTOT + k0 + scs;
      __builtin_amdgcn_global_load_lds(
          (__attribute__((address_space(1))) void*)gp,
          (__attribute__((address_space(3))) void*)&Al[bb][row * 64 + scl], 16, 0, 0);
    }
#pragma unroll
    for (int j = 0; j < 2; ++j) {      // B: 128 rows in 2 passes of 64
      int row = j * 64 + sr;
      const unsigned short* gp = Bbase + (size_t)row * KTOT + k0 + scs;
      __builtin_amdgcn_global_load_lds(
          (__attribute__((address_space(1))) void*)gp,
          (__attribute__((address_space(3))) void*)&Bl[bb][row * 64 + scl], 16, 0, 0);
    }
  };

  auto compute = [&](int bb) {
#pragma unroll
    for (int kk = 0; kk < 2; ++kk) {
      int ko = kk * 32 + (lane >> 4) * 8;
      s16x8 af[4], bfr[4];
#pragma unroll
      for (int m = 0; m < 4; ++m) {
        int row = wm * 64 + m * 16 + (lane & 15);   // row&7 == lane&7
        u32x4 v = *(const u32x4*)&Al[bb][(row * 64 + ko) ^ rxor];
        af[m] = __builtin_bit_cast(s16x8, v);
      }
#pragma unroll
      for (int n = 0; n < 4; ++n) {
        int row = wn * 64 + n * 16 + (lane & 15);
        u32x4 v = *(const u32x4*)&Bl[bb][(row * 64 + ko) ^ rxor];
        bfr[n] = __builtin_bit_cast(s16x8, v);
      }
#pragma unroll
      for (int m = 0; m < 4; ++m)
#pragma unroll
        for (int n = 0; n < 4; ++n)
          acc[m][n] = __builtin_amdgcn_mfma_f32_16x16x32_bf16(af[m], bfr[n], acc[m][n], 0, 0, 0);
    }
  };

  stage(0, kbeg);
  stage(1, kbeg + 64);
  int cur = 0;
#pragma unroll
  for (int s = 0; s < NSTEP; ++s) {
    // retire exactly the current tile's 6 loads; keep next tile's in flight
    if (s + 1 < NSTEP) asm volatile("s_waitcnt vmcnt(6)" ::: "memory");
    else               asm volatile("s_waitcnt vmcnt(0)" ::: "memory");
    __builtin_amdgcn_s_barrier();      // all waves' cur-tile loads landed
    compute(cur);                      // ds_read + MFMA (compiler handles lgkm)
    if (s + 2 < NSTEP) {
      __builtin_amdgcn_s_barrier();    // all waves done READING cur
      stage(cur, kbeg + (s + 2) * 64); // overwrite cur with tile s+2
    }
    cur ^= 1;
  }

  // epilogue: C/D layout col = lane&15, row = (lane>>4)*4 + reg
  int rbase = mt * 256 + wm * 64;
  int cbase = nt * 128 + wn * 64;
#pragma unroll
  for (int m = 0; m < 4; ++m) {
#pragma unroll
    for (int n = 0; n < 4; ++n) {
      int col = cbase + n * 16 + (lane & 15);
      float bv = GELU_OUT ? bias[e * NDIM + col] : 0.f;
#pragma unroll
      for (int r = 0; r < 4; ++r) {
        int row = rbase + m * 16 + (lane >> 4) * 4 + r;
        if (row < Me) {
          float v = acc[m][n][r] + bv;
          size_t idx = ((size_t)part * PAIRS + seg + row) * NDIM + col;
          if constexpr (GELU_OUT) {
            ((unsigned short*)C)[idx] = f2bf(gelu_fast(v));
          } else {
            ((unsigned short*)C)[idx] = f2bf(v);   // bf16 partial; bias in combine
          }
        }
      }
    }
  }
}

// out[t] = w0*(sum_p P[p][s0] + b2[e0]) + w1*(sum_p P[p][s1] + b2[e1]); P is bf16
template <int NSPLIT>
__global__ void k_combine(const unsigned short* __restrict__ P, const int* __restrict__ slot_of,
                          const int* __restrict__ eidx, const float* __restrict__ ew,
                          const float* __restrict__ b2, float* __restrict__ out) {
  int t = blockIdx.x;
  int i = threadIdx.x;  // 192 threads * 4 floats = 768
  int s0 = slot_of[2 * t], s1 = slot_of[2 * t + 1];
  int e0 = eidx[2 * t],    e1 = eidx[2 * t + 1];
  float w0 = ew[2 * t], w1 = ew[2 * t + 1];
  f32x4 a = *(const f32x4*)&b2[e0 * H_DIM + i * 4];
  f32x4 c = *(const f32x4*)&b2[e1 * H_DIM + i * 4];
#pragma unroll
  for (int p = 0; p < NSPLIT; ++p) {
    u16x4 va = *(const u16x4*)&P[((size_t)p * PAIRS + s0) * H_DIM + i * 4];
    u16x4 vb = *(const u16x4*)&P[((size_t)p * PAIRS + s1) * H_DIM + i * 4];
#pragma unroll
    for (int j = 0; j < 4; ++j) { a[j] += bf2f(va[j]); c[j] += bf2f(vb[j]); }
  }
  f32x4 o;
  o[0] = w0 * a[0] + w1 * c[0];
  o[1] = w0 * a[1] + w1 * c[1];
  o[2] = w0 * a[2] + w1 * c[2];
  o[3] = w0 * a[3] + w1 * c[3];
  ((f32x4*)(out + (size_t)t * H_DIM))[i] = o;
}

extern "C" void kernel_launch(void* const* d_in, const int* in_sizes, int n_in,
                              void* d_out, int out_size, void* d_ws, size_t ws_size,
                              hipStream_t stream) {
  (void)in_sizes; (void)n_in; (void)out_size;
  const float* x  = (const float*)d_in[0];
  const float* Wg = (const float*)d_in[1];
  const float* bg = (const float*)d_in[2];
  const float* W1 = (const float*)d_in[3];
  const float* b1 = (const float*)d_in[4];
  const float* W2 = (const float*)d_in[5];
  const float* b2 = (const float*)d_in[6];
  float* out = (float*)d_out;

  char* w = (char*)d_ws;
  size_t off = 0;
  auto take = [&](size_t n) { void* p = w + off; off = (off + n + 255) & ~(size_t)255; return p; };
  int*   ctrl    = (int*)  take(64 * sizeof(int));   // [0..7] counts, [8..15] offsets
  int*   eidx    = (int*)  take(PAIRS * sizeof(int));
  float* ew      = (float*)take(PAIRS * sizeof(float));
  int*   slot_of = (int*)  take(PAIRS * sizeof(int));
  int*   tok_of  = (int*)  take(PAIRS * sizeof(int));
  unsigned short* Xg   = (unsigned short*)take((size_t)PAIRS * H_DIM * 2);
  unsigned short* Wb   = (unsigned short*)take((size_t)E_NUM * H_DIM * DFF * 2);  // W1b then W2b
  unsigned short* Hmid = (unsigned short*)take((size_t)PAIRS * DFF * 2);
  size_t p_off = off;
  unsigned short* P = (unsigned short*)(w + p_off);
  bool split4 = (p_off + (size_t)4 * PAIRS * H_DIM * 2) <= ws_size;
  if (p_off + (size_t)PAIRS * H_DIM * 2 > ws_size) return;

  int* counts  = ctrl;
  int* offsets = ctrl + 8;

  k_route<<<T_NUM / 4, 256, 0, stream>>>(x, Wg, bg, eidx, ew);
  k_build<<<1, 256, 0, stream>>>(eidx, counts, offsets, tok_of, slot_of);
  k_gather<<<PAIRS, 64, 0, stream>>>(x, tok_of, Xg);

  // W1 [E][768][3072] -> Wb [E][3072][768] bf16
  k_transpose_cast<<<dim3(DFF / 64, H_DIM / 64, E_NUM), 256, 0, stream>>>(W1, Wb, H_DIM, DFF);
  // GEMM1: 24 nt * 8 e * 4 mt = 768 blocks (active ~390-580)
  k_gemm<H_DIM, DFF / 128, 1, 4, true><<<(DFF / 128) * E_NUM * 4, 512, 0, stream>>>(
      Xg, Wb, b1, Hmid, counts, offsets);

  // W2 [E][3072][768] -> Wb [E][768][3072] bf16 (reuse; stream order serializes)
  k_transpose_cast<<<dim3(H_DIM / 64, DFF / 64, E_NUM), 256, 0, stream>>>(W2, Wb, DFF, H_DIM);

  if (split4) {
    // GEMM2: 6 nt * 8 e * 4 part * 4 mt = 768 blocks (active ~420)
    k_gemm<DFF, H_DIM / 128, 4, 4, false><<<(H_DIM / 128) * E_NUM * 4 * 4, 512, 0, stream>>>(
        Hmid, Wb, b2, P, counts, offsets);
    k_combine<4><<<T_NUM, 192, 0, stream>>>(P, slot_of, eidx, ew, b2, out);
  } else {
    k_gemm<DFF, H_DIM / 128, 1, 4, false><<<(H_DIM / 128) * E_NUM * 4, 512, 0, stream>>>(
        Hmid, Wb, b2, P, counts, offsets);
    k_combine<1><<<T_NUM, 192, 0, stream>>>(P, slot_of, eidx, ew, b2, out);
  }
}